// Round 5
// baseline (434.595 us; speedup 1.0000x reference)
//
#include <hip/hip_runtime.h>

// CTC batch cost forward, B=256, T=256, C=1000, L=64, S=129, blank=999.
// ROUND 5: kill the scattered gather.
//   Phase 1 (extract): STREAM all of y_pred with dense coalesced float4
//     reads (262 MB at HBM ceiling). Per block: one b, 32 t-rows. A 1000-entry
//     column->slot byte map in LDS (slot = first-occurrence label index,
//     column 999 -> slot 64) lets each thread test its 4 contiguous columns
//     with ONE LDS u32 read; only ~65 hits/row get log()'d and written to the
//     compact V[B*T][RS] table. No divergent loads anywhere.
//   Phase 2 (scan): R4's validated LDS-staged single-wave recursion,
//     re-indexed: odd state of lane i reads slot fp(i) = first occurrence of
//     lab[i]; blank reads slot 64 (LDS broadcast).

#define T_    256
#define C_    1000
#define L_    64
#define BLANK 999       // C-1
#define NEGF  (-1e30f)
#define EPSF  (1e-7f)
#define RS    68        // V row stride (floats): slots 0..63, blank 64, pad
#define CK    64        // t-steps per LDS chunk (phase 2)
#define NV    17        // float4 per lane per chunk: 64*68/(64*4)
#define RPB   32        // t-rows per extractor block

// ---------------- Phase 1: streaming extract + log ----------------
__global__ __launch_bounds__(256)
void ctc_extract_kernel(const int* __restrict__ y_true,
                        const float* __restrict__ y_pred,
                        float* __restrict__ V) {
    __shared__ int          slab[64];
    __shared__ unsigned int sm32[256];     // 1024 slot bytes: col -> slot|0xFF

    const int tid = threadIdx.x;
    const int b   = blockIdx.x >> 3;       // T_/RPB = 8 blocks per b
    const int t0  = (blockIdx.x & 7) * RPB;

    sm32[tid] = 0xFFFFFFFFu;
    if (tid < 64) slab[tid] = y_true[b * L_ + tid];
    __syncthreads();
    if (tid < 64) {
        const int myl = slab[tid];
        int fp = tid;
        for (int j = 0; j < 64; ++j) { if (slab[j] == myl) { fp = j; break; } }
        if (fp == tid) ((unsigned char*)sm32)[myl] = (unsigned char)tid;
    }
    if (tid == 0) ((unsigned char*)sm32)[BLANK] = 64;
    __syncthreads();

    const bool act = tid < 250;            // 250 float4 cover 1000 cols
    const unsigned int sm = sm32[tid];     // slot bytes for cols 4*tid..4*tid+3
    const float* __restrict__ base = y_pred + ((size_t)b * T_ + t0) * C_;

    for (int r0 = 0; r0 < RPB; r0 += 4) {  // 4-row batches => 4 loads in flight
        float4 v[4];
        #pragma unroll
        for (int q = 0; q < 4; ++q) {
            const float* row = base + (size_t)(r0 + q) * C_;
            v[q] = act ? ((const float4*)row)[tid]
                       : make_float4(0.f, 0.f, 0.f, 0.f);
        }
        if (act && sm != 0xFFFFFFFFu) {
            #pragma unroll
            for (int q = 0; q < 4; ++q) {
                float* orow = V + (size_t)(b * T_ + t0 + r0 + q) * RS;
                const float vals[4] = { v[q].x, v[q].y, v[q].z, v[q].w };
                #pragma unroll
                for (int e = 0; e < 4; ++e) {
                    const unsigned int sl = (sm >> (8 * e)) & 0xFFu;
                    if (sl != 0xFFu) orow[sl] = __logf(vals[e] + EPSF);
                }
            }
        }
    }
}

// ---------------- Phase 2: per-row recursion (single wave, LDS-resident) ----
__global__ __launch_bounds__(64)
void ctc_scan_kernel(const int* __restrict__ y_true,
                     const float* __restrict__ lp,
                     float* __restrict__ out) {
    __shared__ float sbuf[2][CK * RS];     // 2 x 17408 B = 34.8 KB

    const int b    = blockIdx.x;
    const int lane = threadIdx.x;          // 0..63

    const float* __restrict__ lrow = lp + (size_t)b * T_ * RS;

    const int lab   = y_true[b * L_ + lane];
    const int labm1 = __shfl_up(lab, 1, 64);
    const bool allow = (lane > 0) && (lab != labm1);

    // fp = first-occurrence label index of this lane's label (slot id).
    int fp = 64;
    for (int j = 0; j < 64; ++j) {
        const int lj = __shfl(lab, j, 64);
        if (fp == 64 && lj == lab) fp = j;
    }

    float aE = NEGF, aO = NEGF, aL = NEGF; // alpha[2i], alpha[2i+1], alpha[128]

    float4 va[NV], vb[NV];

    auto loadChunk = [&](int c, float4 (&v)[NV]) {
        const float4* g = (const float4*)(lrow + (size_t)c * CK * RS);
        #pragma unroll
        for (int k = 0; k < NV; ++k) v[k] = g[k * 64 + lane];
    };
    auto writeChunk = [&](int sel, float4 (&v)[NV]) {
        float4* d = (float4*)&sbuf[sel][0];
        #pragma unroll
        for (int k = 0; k < NV; ++k) d[k * 64 + lane] = v[k];
    };

    auto step = [&](float lpB, float lpL) {
        float upO = __shfl_up(aO, 1, 64);
        if (lane == 0) upO = NEGF;
        // s = 2i (blank): {2i, 2i-1}
        float mE = fmaxf(aE, upO);
        float nE = mE + __logf(__expf(aE - mE) + __expf(upO - mE)) + lpB;
        // s = 2i+1 (label): {2i+1, 2i, 2i-1 if allowed}
        float sk = allow ? upO : NEGF;
        float mO = fmaxf(fmaxf(aO, aE), sk);
        float nO = mO + __logf(__expf(aO - mO) + __expf(aE - mO) +
                               __expf(sk - mO)) + lpL;
        // s = 128 (blank, lane-63 local): {128, 127}
        float mL = fmaxf(aL, aO);
        float nL2 = mL + __logf(__expf(aL - mL) + __expf(aO - mL)) + lpB;
        aE = nE; aO = nO; aL = nL2;
    };

    auto scanChunk = [&](int sel, int rlo) {
        const float* B = &sbuf[sel][0];
        float rB0 = B[rlo * RS + 64],       rL0 = B[rlo * RS + fp];
        float rB1 = B[(rlo + 1) * RS + 64], rL1 = B[(rlo + 1) * RS + fp];
        for (int j = rlo; j < CK; ++j) {
            const float lpB = rB0, lpL = rL0;
            rB0 = rB1; rL0 = rL1;
            int nr = j + 2; if (nr > CK - 1) nr = CK - 1;
            rB1 = B[nr * RS + 64]; rL1 = B[nr * RS + fp];
            step(lpB, lpL);
        }
    };

    loadChunk(0, va); writeChunk(0, va);
    loadChunk(1, vb);

    // t = 0 init: alpha[0] = lp_blank(0) (slot 64), alpha[1] = lp(lab0) (slot 0).
    aE = (lane == 0) ? sbuf[0][64] : NEGF;
    aO = (lane == 0) ? sbuf[0][0]  : NEGF;

    scanChunk(0, 1);                        // t = 1..63
    writeChunk(1, vb);
    loadChunk(2, va);
    scanChunk(1, 0);                        // t = 64..127
    writeChunk(0, va);
    loadChunk(3, vb);
    scanChunk(0, 0);                        // t = 128..191
    writeChunk(1, vb);
    scanChunk(1, 0);                        // t = 192..255

    if (lane == 63) {
        const float m = fmaxf(aL, aO);
        out[b] = -(m + __logf(__expf(aL - m) + __expf(aO - m)));
    }
}

extern "C" void kernel_launch(void* const* d_in, const int* in_sizes, int n_in,
                              void* d_out, int out_size, void* d_ws, size_t ws_size,
                              hipStream_t stream) {
    const int*   y_true = (const int*)d_in[0];
    const float* y_pred = (const float*)d_in[1];
    float*       out    = (float*)d_out;
    float*       V      = (float*)d_ws;   // 256*256*68*4 = 17.8 MB
    (void)in_sizes; (void)n_in; (void)ws_size; (void)out_size;

    ctc_extract_kernel<<<dim3(256 * (T_ / RPB)), dim3(256), 0, stream>>>(y_true, y_pred, V);
    ctc_scan_kernel<<<dim3(256), dim3(64), 0, stream>>>(y_true, V, out);
}

// Round 6
// 374.669 us; speedup vs baseline: 1.1599x; 1.1599x over previous
//
#include <hip/hip_runtime.h>

// CTC batch cost forward, B=256, T=256, C=1000, L=64, S=129, blank=999.
// ROUND 6: linear-domain scan (scaled-CTC). The 255-step recursion chain is
// now shfl + 2 adds + 1 mul (NO transcendentals on the chain). Every 8 steps
// a wave-max butterfly renormalizes alpha and accumulates log(scale).
//   Phase 1: scattered gather (R4-validated, fastest variant) of p+eps into
//            compact V[B*T][RS] — no log needed anymore.
//   Phase 2: one wave per row; whole 69.6 KB strip staged to LDS upfront via
//            global_load_lds (16B); flat t-loop with 4-deep LDS read ring.

#define T_    256
#define C_    1000
#define L_    64
#define BLANK 999       // C-1
#define EPSF  (1e-7f)
#define RS    68        // V row stride (floats): [blank, lab0..lab63, pad x3]
#define NCHUNK ((T_ * RS) / 256)   // 68 x 1KB staging chunks

// ---------------- Phase 1: gather p+eps ----------------
__global__ __launch_bounds__(256)
void ctc_gather_kernel(const int* __restrict__ y_true,
                       const float* __restrict__ y_pred,
                       float* __restrict__ V) {
    const int wave = threadIdx.x >> 6;            // 0..3
    const int lane = threadIdx.x & 63;
    const int pair = blockIdx.x * 4 + wave;       // b*T + t
    const int b = pair >> 8;

    const int lab = y_true[b * L_ + lane];        // coalesced, cache-hot
    const float* __restrict__ row = y_pred + (size_t)pair * C_;
    float* __restrict__ orow = V + (size_t)pair * RS;

    orow[1 + lane] = row[lab] + EPSF;             // scattered 4B gather
    if (lane == 0) orow[0] = row[BLANK] + EPSF;
}

// ---------------- Phase 2: linear-domain recursion ----------------
__global__ __launch_bounds__(64)
void ctc_scan_kernel(const int* __restrict__ y_true,
                     const float* __restrict__ V,
                     float* __restrict__ out) {
    __shared__ float sb[T_ * RS];                 // 69632 B

    const int b    = blockIdx.x;
    const int lane = threadIdx.x;                 // 0..63

    const float* __restrict__ strip = V + (size_t)b * T_ * RS;

    // Stage the whole strip into LDS (68 x 1KB async direct-to-LDS).
#if __has_builtin(__builtin_amdgcn_global_load_lds)
    typedef const __attribute__((address_space(1))) float gfloat;
    typedef __attribute__((address_space(3))) float sfloat;
    #pragma unroll
    for (int k = 0; k < NCHUNK; ++k) {
        __builtin_amdgcn_global_load_lds((gfloat*)(strip + k * 256 + lane * 4),
                                         (sfloat*)(sb + k * 256), 16, 0, 0);
    }
    asm volatile("s_waitcnt vmcnt(0)" ::: "memory");
#else
    #pragma unroll
    for (int k = 0; k < NCHUNK; ++k)
        ((float4*)sb)[k * 64 + lane] = ((const float4*)strip)[k * 64 + lane];
    __syncthreads();
#endif

    const int lab   = y_true[b * L_ + lane];
    const int labm1 = __shfl_up(lab, 1, 64);
    const bool allow = (lane > 0) && (lab != labm1);

    // Linear-domain alphas: lane i holds A[2i] (aE), A[2i+1] (aO);
    // lane 63 additionally the real A[128] (aL). Unreachable = exact 0.
    float aE = 0.f, aO = 0.f, aL = 0.f, lsum = 0.f;
    if (lane == 0) { aE = sb[0]; aO = sb[1]; }

    // 4-deep LDS read ring for the multipliers.
    float rB[4], rL[4];
    #pragma unroll
    for (int k = 0; k < 4; ++k) {
        rB[k] = sb[(1 + k) * RS];                 // broadcast (same addr)
        rL[k] = sb[(1 + k) * RS + 1 + lane];      // 2-way alias: free
    }

    for (int t0 = 1; t0 < T_; t0 += 4) {
        #pragma unroll
        for (int j = 0; j < 4; ++j) {
            const int t = t0 + j;
            if (t >= T_) break;                   // uniform
            const float pB = rB[j], pL = rL[j];
            int tn = t + 4; if (tn > T_ - 1) tn = T_ - 1;
            rB[j] = sb[tn * RS];
            rL[j] = sb[tn * RS + 1 + lane];

            float upO = __shfl_up(aO, 1, 64);     // A_old[2i-1]
            if (lane == 0) upO = 0.f;

            const float nE = (aE + upO) * pB;             // s=2i (blank)
            const float sk = allow ? upO : 0.f;
            const float nO = (aO + aE + sk) * pL;         // s=2i+1 (label)
            const float nL = (aL + aO) * pB;              // s=128 (lane63)
            aE = nE; aO = nO; aL = nL;

            if ((t & 7) == 0) {                   // renormalize every 8 steps
                float m = fmaxf(fmaxf(aE, aO), aL);
                #pragma unroll
                for (int d = 1; d < 64; d <<= 1)
                    m = fmaxf(m, __shfl_xor(m, d, 64));
                const float r = __builtin_amdgcn_rcpf(m);
                aE *= r; aO *= r; aL *= r;
                lsum += __logf(m);                // off the critical chain
            }
        }
    }

    if (lane == 63) {
        // loss = -( log(A[128] + A[127]) + sum of log scales )
        out[b] = -(__logf(aL + aO) + lsum);
    }
}

extern "C" void kernel_launch(void* const* d_in, const int* in_sizes, int n_in,
                              void* d_out, int out_size, void* d_ws, size_t ws_size,
                              hipStream_t stream) {
    const int*   y_true = (const int*)d_in[0];
    const float* y_pred = (const float*)d_in[1];
    float*       out    = (float*)d_out;
    float*       V      = (float*)d_ws;           // 256*256*68*4 = 17.8 MB
    (void)in_sizes; (void)n_in; (void)ws_size; (void)out_size;

    ctc_gather_kernel<<<dim3((256 * T_) / 4), dim3(256), 0, stream>>>(y_true, y_pred, V);
    ctc_scan_kernel<<<dim3(256), dim3(64), 0, stream>>>(y_true, V, out);
}